// Round 1
// baseline (12.674 us; speedup 1.0000x reference)
//
#include <hip/hip_runtime.h>

// Problem geometry (from reference): x is (B, H, T) = (4096, 1024, 26) f32.
// Only x[b, j, 6:12] for j in [0,26) is used:
//   q[b, j, k] = x[b, j, 6+k],  k in [0,6)
// cost(b,j) = 1/denom via Sherman-Morrison on M = 2I + 0.5 c c^T:
//   denom = 0.5*sum(L^2 s^2) - 0.125*(sum(L s c))^2 / (1 + 0.25*sum(c^2))
// Output = scalar sum over all (b, j).

#define T_DIM 26
#define H_DIM 1024
#define TASKS_PER_B 26
#define BLK 256

__global__ void cost_partial_kernel(const float* __restrict__ x,
                                    double* __restrict__ partial,
                                    int ntasks) {
    __shared__ double red[BLK / 64];
    const int gsize = gridDim.x * blockDim.x;
    double acc = 0.0;

    for (int t = blockIdx.x * blockDim.x + threadIdx.x; t < ntasks; t += gsize) {
        const int b = t / TASKS_PER_B;
        const int j = t - b * TASKS_PER_B;
        const float* q = x + (size_t)b * (H_DIM * T_DIM) + (size_t)j * T_DIM + 6;

        double cq = 0.0;
        double sL2s2 = 0.0, sLsc = 0.0, sc2 = 0.0;
#pragma unroll
        for (int i = 0; i < 6; ++i) {
            // L[i] as the reference computes it in f32: (i+1)*0.1f + 0.3f
            const double Li = (double)((float)(i + 1) * 0.1f + 0.3f);
            cq += (double)q[i];
            double s, c;
            s = sin(cq);
            c = cos(cq);
            sL2s2 += Li * Li * s * s;
            sLsc  += Li * s * c;
            sc2   += c * c;
        }
        const double denom = 0.5 * sL2s2 - 0.125 * sLsc * sLsc / (1.0 + 0.25 * sc2);
        acc += 1.0 / denom;
    }

    // wave-64 butterfly reduce
#pragma unroll
    for (int off = 32; off >= 1; off >>= 1)
        acc += __shfl_down(acc, off, 64);

    const int lane = threadIdx.x & 63;
    const int wid  = threadIdx.x >> 6;
    if (lane == 0) red[wid] = acc;
    __syncthreads();
    if (threadIdx.x == 0) {
        double s = 0.0;
#pragma unroll
        for (int w = 0; w < BLK / 64; ++w) s += red[w];
        partial[blockIdx.x] = s;
    }
}

__global__ void cost_final_kernel(const double* __restrict__ partial,
                                  int n,
                                  float* __restrict__ out) {
    __shared__ double red[BLK / 64];
    double acc = 0.0;
    for (int i = threadIdx.x; i < n; i += blockDim.x) acc += partial[i];
#pragma unroll
    for (int off = 32; off >= 1; off >>= 1)
        acc += __shfl_down(acc, off, 64);
    const int lane = threadIdx.x & 63;
    const int wid  = threadIdx.x >> 6;
    if (lane == 0) red[wid] = acc;
    __syncthreads();
    if (threadIdx.x == 0) {
        double s = 0.0;
#pragma unroll
        for (int w = 0; w < BLK / 64; ++w) s += red[w];
        out[0] = (float)s;
    }
}

extern "C" void kernel_launch(void* const* d_in, const int* in_sizes, int n_in,
                              void* d_out, int out_size, void* d_ws, size_t ws_size,
                              hipStream_t stream) {
    const float* x = (const float*)d_in[0];
    // d_in[1] = cond (unused), d_in[2] = time (gives B)
    const int B = in_sizes[2];
    const int ntasks = B * TASKS_PER_B;

    int nblocks = (ntasks + BLK - 1) / BLK;
    // d_ws must hold nblocks doubles; clamp if scratch is tiny (grid-stride
    // loop in the kernel keeps correctness either way).
    const int max_blocks_ws = (int)(ws_size / sizeof(double));
    if (nblocks > max_blocks_ws) nblocks = max_blocks_ws > 0 ? max_blocks_ws : 1;

    double* partial = (double*)d_ws;
    float* out = (float*)d_out;

    cost_partial_kernel<<<nblocks, BLK, 0, stream>>>(x, partial, ntasks);
    cost_final_kernel<<<1, BLK, 0, stream>>>(partial, nblocks, out);
}